// Round 5
// baseline (267.913 us; speedup 1.0000x reference)
//
#include <hip/hip_runtime.h>

#define NMET 200000
#define NRXN 400000
#define ESUB 800000
#define EALL 1600000
#define NXCD 8
#define NBLK ((NRXN + 255) / 256)   // 1563 scan blocks

// c_target = 1 + 0.5*sin(2*pi*100/1000) = 1.2938926261462366
#define C_TARGET 1.29389262614623664f
#define DT_C 0.01f
#define HOMEO_C 0.1f
#define LOG2_10 3.32192809488736235f

__device__ __forceinline__ float fast_tanh(float x) {
    float e = __expf(2.0f * x);
    return 1.0f - 2.0f * __builtin_amdgcn_rcpf(e + 1.0f);
}

// True XCD id of the executing wave (wave-uniform SGPR). NEVER bid%8: the
// workgroup->XCD mapping is undefined, and L2-scope atomics are only atomic
// among waves on the SAME XCD.
__device__ __forceinline__ int xcc_id() {
    unsigned id;
    asm("s_getreg_b32 %0, hwreg(HW_REG_XCC_ID)" : "=s"(id));
    return (int)(id & 7u);
}

// L2-scope atomics: no sc1 -> executed at the XCD's L2 (coherent for all CUs
// on that XCD). Only valid because each plane is written solely by its XCD.
__device__ __forceinline__ void atomL2add_f(float* p, float v) {
    __hip_atomic_fetch_add(p, v, __ATOMIC_RELAXED, __HIP_MEMORY_SCOPE_WORKGROUP);
}
__device__ __forceinline__ int atomL2add_i(int* p, int v) {
    return __hip_atomic_fetch_add(p, v, __ATOMIC_RELAXED, __HIP_MEMORY_SCOPE_WORKGROUP);
}

// ---- 1. fused: per-XCD histogram + edge MLP (coalesced edge-order msg) -----
__global__ __launch_bounds__(256) void k_hist_msg(
    const float* __restrict__ x, const int* __restrict__ met_sub,
    const int* __restrict__ rxn_sub, const float* __restrict__ sto_sub,
    const float* __restrict__ sub_w1, const float* __restrict__ sub_b1,
    const float* __restrict__ sub_w2,
    int* __restrict__ cntP, int* __restrict__ rank, int* __restrict__ xcd_e,
    float* __restrict__ msg, float* __restrict__ ext_e)
{
    __shared__ float sW1[128];
    __shared__ float sB1[64];
    __shared__ __align__(16) float sW2[512];
    int t = threadIdx.x;
    for (int i = t; i < 128; i += 256) sW1[i] = sub_w1[i];
    for (int i = t; i < 64;  i += 256) sB1[i] = sub_b1[i];
    for (int i = t; i < 512; i += 256) sW2[i] = sub_w2[i];
    __syncthreads();

    int e = blockIdx.x * 256 + t;
    if (e >= ESUB) return;
    int r = rxn_sub[e];
    int xcc = xcc_id();
    rank[e] = atomL2add_i(&cntP[(size_t)xcc * NRXN + r], 1);
    xcd_e[e] = xcc;

    int m = met_sub[e];
    float st = sto_sub[e];
    float c  = x[(size_t)m * 8 + 3];
    float ex = x[(size_t)m * 8 + 4];

    float m0 = 0.f, m1 = 0.f, m2 = 0.f, m3 = 0.f;
    float m4 = 0.f, m5 = 0.f, m6 = 0.f, m7 = 0.f;
    #pragma unroll 8
    for (int j = 0; j < 64; ++j) {
        float z = fmaf(c, sW1[j], fmaf(st, sW1[64 + j], sB1[j]));
        float th = fast_tanh(z);
        float4 wa = *(const float4*)&sW2[j * 8];
        float4 wb = *(const float4*)&sW2[j * 8 + 4];
        m0 = fmaf(th, wa.x, m0); m1 = fmaf(th, wa.y, m1);
        m2 = fmaf(th, wa.z, m2); m3 = fmaf(th, wa.w, m3);
        m4 = fmaf(th, wb.x, m4); m5 = fmaf(th, wb.y, m5);
        m6 = fmaf(th, wb.z, m6); m7 = fmaf(th, wb.w, m7);
    }
    float4* mp = (float4*)&msg[(size_t)e * 8];
    mp[0] = make_float4(m0, m1, m2, m3);
    mp[1] = make_float4(m4, m5, m6, m7);
    ext_e[e] = ex;
}

// ---- 2. plane-prefix cntP in place, cnt_total, per-block sums --------------
__global__ __launch_bounds__(256) void k_bsum(
    int* __restrict__ cntP, int* __restrict__ cnt_total, int* __restrict__ bsum)
{
    __shared__ int lds[256];
    int i = blockIdx.x * 256 + threadIdx.x;
    int s = 0;
    if (i < NRXN) {
        #pragma unroll
        for (int xp = 0; xp < NXCD; ++xp) {
            int c = cntP[(size_t)xp * NRXN + i];
            cntP[(size_t)xp * NRXN + i] = s;   // exclusive prefix over planes
            s += c;
        }
        cnt_total[i] = s;
    }
    lds[threadIdx.x] = (i < NRXN) ? s : 0;
    __syncthreads();
    for (int off = 128; off > 0; off >>= 1) {
        if (threadIdx.x < off) lds[threadIdx.x] += lds[threadIdx.x + off];
        __syncthreads();
    }
    if (threadIdx.x == 0) bsum[blockIdx.x] = lds[0];
}

// ---- 3. single-block exclusive scan of the block sums ----------------------
__global__ __launch_bounds__(256) void k_scan_top(
    const int* __restrict__ bsum, int* __restrict__ boff, int nb)
{
    __shared__ int lds[256];
    __shared__ int carry_s;
    if (threadIdx.x == 0) carry_s = 0;
    __syncthreads();
    for (int base = 0; base < nb; base += 256) {
        int i = base + threadIdx.x;
        int val = (i < nb) ? bsum[i] : 0;
        lds[threadIdx.x] = val;
        __syncthreads();
        for (int off = 1; off < 256; off <<= 1) {
            int add = (threadIdx.x >= off) ? lds[threadIdx.x - off] : 0;
            __syncthreads();
            lds[threadIdx.x] += add;
            __syncthreads();
        }
        int incl = lds[threadIdx.x];
        int carry = carry_s;
        if (i < nb) boff[i] = carry + incl - val;
        __syncthreads();
        if (threadIdx.x == 255) carry_s = carry + incl;
        __syncthreads();
    }
}

// ---- 4. per-reaction global offsets (block scan + boff) --------------------
__global__ __launch_bounds__(256) void k_offsets(
    const int* __restrict__ cnt_total, const int* __restrict__ boff,
    int* __restrict__ offset)
{
    __shared__ int lds[256];
    int i = blockIdx.x * 256 + threadIdx.x;
    int val = (i < NRXN) ? cnt_total[i] : 0;
    lds[threadIdx.x] = val;
    __syncthreads();
    for (int off = 1; off < 256; off <<= 1) {
        int add = (threadIdx.x >= off) ? lds[threadIdx.x - off] : 0;
        __syncthreads();
        lds[threadIdx.x] += add;
        __syncthreads();
    }
    if (i < NRXN) offset[i] = boff[blockIdx.x] + lds[threadIdx.x] - val;
}

// ---- 5. scatter edge ids into CSR slots (plain stores) ---------------------
__global__ __launch_bounds__(256) void k_scatter(
    const int* __restrict__ rxn_sub, const int* __restrict__ offset,
    const int* __restrict__ cntP, const int* __restrict__ rank,
    const int* __restrict__ xcd_e, int* __restrict__ slot_edge)
{
    int e = blockIdx.x * 256 + threadIdx.x;
    if (e >= ESUB) return;
    int r = rxn_sub[e];
    int xcc = xcd_e[e];
    int slot = offset[r] + cntP[(size_t)xcc * NRXN + r] + rank[e];
    slot_edge[slot] = e;
}

// ---- 6. per-reaction: gather msgs, rate MLP, v, consume (L2 planes) --------
__global__ __launch_bounds__(256) void k_rxn3(
    const int* __restrict__ cnt_total, const int* __restrict__ offset,
    const int* __restrict__ slot_edge,
    const float* __restrict__ msg, const float* __restrict__ ext_e,
    const int* __restrict__ met_sub, const float* __restrict__ sto_sub,
    const float* __restrict__ sub_b2,
    const float* __restrict__ rate_w1, const float* __restrict__ rate_b1,
    const float* __restrict__ rate_w2, const float* __restrict__ rate_b2,
    const float* __restrict__ log_k,
    float* __restrict__ v, float* __restrict__ totalP)
{
    __shared__ __align__(16) float sR1[512];
    __shared__ float sRB1[64];
    __shared__ float sR2[64];
    __shared__ float sB2[8];
    __shared__ float sRB2;
    int t = threadIdx.x;
    for (int i = t; i < 512; i += 256) sR1[i] = rate_w1[i];
    for (int i = t; i < 64;  i += 256) { sRB1[i] = rate_b1[i]; sR2[i] = rate_w2[i]; }
    if (t < 8) sB2[t] = sub_b2[t];
    if (t == 64) sRB2 = rate_b2[0];
    __syncthreads();

    int r = blockIdx.x * 256 + t;
    if (r >= NRXN) return;
    int n = cnt_total[r];
    int base = offset[r];
    float fn = (float)n;

    float h0 = fn * sB2[0], h1 = fn * sB2[1], h2 = fn * sB2[2], h3 = fn * sB2[3];
    float h4 = fn * sB2[4], h5 = fn * sB2[5], h6 = fn * sB2[6], h7 = fn * sB2[7];
    float exs = 0.f;
    for (int i = 0; i < n; ++i) {
        int e = slot_edge[base + i];
        const float4* mp = (const float4*)&msg[(size_t)e * 8];
        float4 a = mp[0], b = mp[1];
        h0 += a.x; h1 += a.y; h2 += a.z; h3 += a.w;
        h4 += b.x; h5 += b.y; h6 += b.z; h7 += b.w;
        exs += ext_e[e];
    }

    float acc = sRB2;
    #pragma unroll 4
    for (int j = 0; j < 64; ++j) {
        float z = sRB1[j];
        z = fmaf(h0, sR1[j],       z);
        z = fmaf(h1, sR1[64 + j],  z);
        z = fmaf(h2, sR1[128 + j], z);
        z = fmaf(h3, sR1[192 + j], z);
        z = fmaf(h4, sR1[256 + j], z);
        z = fmaf(h5, sR1[320 + j], z);
        z = fmaf(h6, sR1[384 + j], z);
        z = fmaf(h7, sR1[448 + j], z);
        acc = fmaf(fast_tanh(z), sR2[j], acc);
    }
    float nmax = fmaxf(fn, 1.0f);
    float ext_mean = 2.0f * exs * __builtin_amdgcn_rcpf(nmax);
    float kk = exp2f(log_k[r] * LOG2_10);
    float vr = kk * ext_mean * acc;
    v[r] = vr;

    // consumption scatter into this XCD's plane (pre-limit v, per reference)
    int xcc = xcc_id();
    float* tp = totalP + (size_t)xcc * NMET;
    float cterm = vr * DT_C;
    for (int i = 0; i < n; ++i) {
        int e = slot_edge[base + i];
        atomL2add_f(&tp[met_sub[e]], sto_sub[e] * cterm);
    }
}

// ---- 7. reduce totalP planes -> met_scale ----------------------------------
__global__ __launch_bounds__(256) void k_met(
    const float* __restrict__ x, const float* __restrict__ totalP,
    float* __restrict__ met_scale)
{
    int m = blockIdx.x * 256 + threadIdx.x;
    if (m >= NMET) return;
    float tot = 0.f;
    #pragma unroll
    for (int xp = 0; xp < NXCD; ++xp) tot += totalP[(size_t)xp * NMET + m];
    float c = x[(size_t)m * 8 + 3];
    float ms = 1.0f;
    if (tot > 1e-12f) ms = fminf(c / tot, 1.0f);
    met_scale[m] = ms;
}

// ---- 8. per-reaction min over edges + v scale ------------------------------
__global__ __launch_bounds__(256) void k_rscale(
    const int* __restrict__ cnt_total, const int* __restrict__ offset,
    const int* __restrict__ slot_edge, const int* __restrict__ met_sub,
    const float* __restrict__ met_scale, float* __restrict__ v)
{
    int r = blockIdx.x * 256 + threadIdx.x;
    if (r >= NRXN) return;
    int n = cnt_total[r];
    int base = offset[r];
    float ms = 1.0f;
    for (int i = 0; i < n; ++i) {
        int e = slot_edge[base + i];
        ms = fminf(ms, met_scale[met_sub[e]]);
    }
    v[r] *= ms;
}

// ---- 9. final scatter-add into per-XCD out planes --------------------------
__global__ __launch_bounds__(256) void k_contrib(
    const int* __restrict__ met_all, const int* __restrict__ rxn_all,
    const float* __restrict__ sto_all, const float* __restrict__ v,
    float* __restrict__ outP)
{
    int e = blockIdx.x * 256 + threadIdx.x;
    if (e >= EALL) return;
    int xcc = xcc_id();
    float* op = outP + (size_t)xcc * NMET;
    atomL2add_f(&op[met_all[e]], sto_all[e] * v[rxn_all[e]]);
}

// ---- 10. reduce out planes + homeostasis -----------------------------------
__global__ __launch_bounds__(256) void k_finish(
    const float* __restrict__ x, const float* __restrict__ outP,
    float* __restrict__ out)
{
    int m = blockIdx.x * 256 + threadIdx.x;
    if (m >= NMET) return;
    float s = 0.f;
    #pragma unroll
    for (int xp = 0; xp < NXCD; ++xp) s += outP[(size_t)xp * NMET + m];
    float c = x[(size_t)m * 8 + 3];
    out[m] = s - HOMEO_C * (c - C_TARGET);
}

extern "C" void kernel_launch(void* const* d_in, const int* in_sizes, int n_in,
                              void* d_out, int out_size, void* d_ws, size_t ws_size,
                              hipStream_t stream) {
    const float* x       = (const float*)d_in[0];
    const int*   met_sub = (const int*)  d_in[1];
    const int*   rxn_sub = (const int*)  d_in[2];
    const float* sto_sub = (const float*)d_in[3];
    const int*   met_all = (const int*)  d_in[4];
    const int*   rxn_all = (const int*)  d_in[5];
    const float* sto_all = (const float*)d_in[6];
    const float* sub_w1  = (const float*)d_in[7];
    const float* sub_b1  = (const float*)d_in[8];
    const float* sub_w2  = (const float*)d_in[9];
    const float* sub_b2  = (const float*)d_in[10];
    const float* rate_w1 = (const float*)d_in[11];
    const float* rate_b1 = (const float*)d_in[12];
    const float* rate_w2 = (const float*)d_in[13];
    const float* rate_b2 = (const float*)d_in[14];
    const float* log_k   = (const float*)d_in[15];

    char* ws = (char*)d_ws;
    // ---- zeroed region (atomic accumulators), contiguous at ws start ----
    int*   cntP   = (int*)ws;                            // 8*NRXN  [zeroed]
    float* totalP = (float*)(cntP + (size_t)NXCD * NRXN);// 8*NMET  [zeroed]
    float* outP   = totalP + (size_t)NXCD * NMET;        // 8*NMET  [zeroed]
    // ---- fully-overwritten region ----
    int*   rank      = (int*)(outP + (size_t)NXCD * NMET); // ESUB
    int*   xcd_e     = rank + ESUB;                        // ESUB
    int*   cnt_total = xcd_e + ESUB;                       // NRXN
    int*   offset    = cnt_total + NRXN;                   // NRXN
    int*   bsum      = offset + NRXN;                      // 2048
    int*   boff      = bsum + 2048;                        // 2048
    int*   slot_edge = boff + 2048;                        // ESUB
    float* msg       = (float*)(slot_edge + ESUB);         // ESUB*8
    float* ext_e     = msg + (size_t)ESUB * 8;             // ESUB
    float* v         = ext_e + ESUB;                       // NRXN
    float* met_scale = v + NRXN;                           // NMET
    float* out       = (float*)d_out;

    size_t zero_bytes = ((size_t)NXCD * NRXN + 2 * (size_t)NXCD * NMET) * 4;
    hipMemsetAsync(d_ws, 0, zero_bytes, stream);

    dim3 blk(256);
    k_hist_msg<<<dim3((ESUB + 255) / 256), blk, 0, stream>>>(
        x, met_sub, rxn_sub, sto_sub, sub_w1, sub_b1, sub_w2,
        cntP, rank, xcd_e, msg, ext_e);
    k_bsum<<<dim3(NBLK), blk, 0, stream>>>(cntP, cnt_total, bsum);
    k_scan_top<<<dim3(1), blk, 0, stream>>>(bsum, boff, NBLK);
    k_offsets<<<dim3(NBLK), blk, 0, stream>>>(cnt_total, boff, offset);
    k_scatter<<<dim3((ESUB + 255) / 256), blk, 0, stream>>>(
        rxn_sub, offset, cntP, rank, xcd_e, slot_edge);
    k_rxn3<<<dim3((NRXN + 255) / 256), blk, 0, stream>>>(
        cnt_total, offset, slot_edge, msg, ext_e, met_sub, sto_sub, sub_b2,
        rate_w1, rate_b1, rate_w2, rate_b2, log_k, v, totalP);
    k_met<<<dim3((NMET + 255) / 256), blk, 0, stream>>>(x, totalP, met_scale);
    k_rscale<<<dim3((NRXN + 255) / 256), blk, 0, stream>>>(
        cnt_total, offset, slot_edge, met_sub, met_scale, v);
    k_contrib<<<dim3((EALL + 255) / 256), blk, 0, stream>>>(
        met_all, rxn_all, sto_all, v, outP);
    k_finish<<<dim3((NMET + 255) / 256), blk, 0, stream>>>(x, outP, out);
}

// Round 6
// 224.549 us; speedup vs baseline: 1.1931x; 1.1931x over previous
//
#include <hip/hip_runtime.h>

#define NMET 200000
#define NRXN 400000
#define ESUB 800000
#define EALL 1600000
#define NBLK ((NRXN + 255) / 256)   // 1563 scan blocks (rxn CSR)

// bucket sort for contrib: bucket = met >> 9  (512 mets / bucket)
#define BSHIFT 9
#define NBUCK 391                    // ceil(200000 / 512)
#define EB 8192                      // edges per sort block
#define NB 196                       // ceil(EALL / EB)

// c_target = 1 + 0.5*sin(2*pi*100/1000) = 1.2938926261462366
#define C_TARGET 1.29389262614623664f
#define DT_C 0.01f
#define HOMEO_C 0.1f
#define LOG2_10 3.32192809488736235f

__device__ __forceinline__ float fast_tanh(float x) {
    float e = __expf(2.0f * x);
    return 1.0f - 2.0f * __builtin_amdgcn_rcpf(e + 1.0f);
}

// ---- 1. fused: histogram atomic (wall) + edge MLP (hidden under it) --------
__global__ __launch_bounds__(256) void k_hist_msg(
    const float* __restrict__ x, const int* __restrict__ met_sub,
    const int* __restrict__ rxn_sub, const float* __restrict__ sto_sub,
    const float* __restrict__ sub_w1, const float* __restrict__ sub_b1,
    const float* __restrict__ sub_w2,
    int* __restrict__ cnt, int* __restrict__ rank,
    float* __restrict__ msg, float* __restrict__ ext_e)
{
    __shared__ float sW1[128];
    __shared__ float sB1[64];
    __shared__ __align__(16) float sW2[512];
    int t = threadIdx.x;
    for (int i = t; i < 128; i += 256) sW1[i] = sub_w1[i];
    for (int i = t; i < 64;  i += 256) sB1[i] = sub_b1[i];
    for (int i = t; i < 512; i += 256) sW2[i] = sub_w2[i];
    __syncthreads();

    int e = blockIdx.x * 256 + t;
    if (e >= ESUB) return;
    int r = rxn_sub[e];
    rank[e] = atomicAdd(&cnt[r], 1);

    int m = met_sub[e];
    float st = sto_sub[e];
    float c  = x[(size_t)m * 8 + 3];
    float ex = x[(size_t)m * 8 + 4];

    float m0 = 0.f, m1 = 0.f, m2 = 0.f, m3 = 0.f;
    float m4 = 0.f, m5 = 0.f, m6 = 0.f, m7 = 0.f;
    #pragma unroll 8
    for (int j = 0; j < 64; ++j) {
        float z = fmaf(c, sW1[j], fmaf(st, sW1[64 + j], sB1[j]));
        float th = fast_tanh(z);
        float4 wa = *(const float4*)&sW2[j * 8];
        float4 wb = *(const float4*)&sW2[j * 8 + 4];
        m0 = fmaf(th, wa.x, m0); m1 = fmaf(th, wa.y, m1);
        m2 = fmaf(th, wa.z, m2); m3 = fmaf(th, wa.w, m3);
        m4 = fmaf(th, wb.x, m4); m5 = fmaf(th, wb.y, m5);
        m6 = fmaf(th, wb.z, m6); m7 = fmaf(th, wb.w, m7);
    }
    float4* mp = (float4*)&msg[(size_t)e * 8];
    mp[0] = make_float4(m0, m1, m2, m3);
    mp[1] = make_float4(m4, m5, m6, m7);
    ext_e[e] = ex;
}

// ---- 2. per-256-block sums of cnt (rxn CSR) --------------------------------
__global__ __launch_bounds__(256) void k_bsum(
    const int* __restrict__ cnt, int* __restrict__ bsum)
{
    __shared__ int lds[256];
    int i = blockIdx.x * 256 + threadIdx.x;
    lds[threadIdx.x] = (i < NRXN) ? cnt[i] : 0;
    __syncthreads();
    for (int off = 128; off > 0; off >>= 1) {
        if (threadIdx.x < off) lds[threadIdx.x] += lds[threadIdx.x + off];
        __syncthreads();
    }
    if (threadIdx.x == 0) bsum[blockIdx.x] = lds[0];
}

// ---- 3. single-block exclusive scan of the block sums ----------------------
__global__ __launch_bounds__(256) void k_scan_top(
    const int* __restrict__ bsum, int* __restrict__ boff, int nb)
{
    __shared__ int lds[256];
    __shared__ int carry_s;
    if (threadIdx.x == 0) carry_s = 0;
    __syncthreads();
    for (int base = 0; base < nb; base += 256) {
        int i = base + threadIdx.x;
        int val = (i < nb) ? bsum[i] : 0;
        lds[threadIdx.x] = val;
        __syncthreads();
        for (int off = 1; off < 256; off <<= 1) {
            int add = (threadIdx.x >= off) ? lds[threadIdx.x - off] : 0;
            __syncthreads();
            lds[threadIdx.x] += add;
            __syncthreads();
        }
        int incl = lds[threadIdx.x];
        int carry = carry_s;
        if (i < nb) boff[i] = carry + incl - val;
        __syncthreads();
        if (threadIdx.x == 255) carry_s = carry + incl;
        __syncthreads();
    }
}

// ---- 4. per-reaction global offsets (block scan + boff) --------------------
__global__ __launch_bounds__(256) void k_offsets(
    const int* __restrict__ cnt, const int* __restrict__ boff,
    int* __restrict__ offset)
{
    __shared__ int lds[256];
    int i = blockIdx.x * 256 + threadIdx.x;
    int val = (i < NRXN) ? cnt[i] : 0;
    lds[threadIdx.x] = val;
    __syncthreads();
    for (int off = 1; off < 256; off <<= 1) {
        int add = (threadIdx.x >= off) ? lds[threadIdx.x - off] : 0;
        __syncthreads();
        lds[threadIdx.x] += add;
        __syncthreads();
    }
    if (i < NRXN) offset[i] = boff[blockIdx.x] + lds[threadIdx.x] - val;
}

// ---- 5. scatter edge ids into CSR slots (plain stores) ---------------------
__global__ __launch_bounds__(256) void k_scatter(
    const int* __restrict__ rxn_sub, const int* __restrict__ offset,
    const int* __restrict__ rank, int* __restrict__ slot_edge)
{
    int e = blockIdx.x * 256 + threadIdx.x;
    if (e >= ESUB) return;
    slot_edge[offset[rxn_sub[e]] + rank[e]] = e;
}

// ---- 6. per-reaction: gather msgs, rate MLP, v, consume --------------------
__global__ __launch_bounds__(256) void k_rxn3(
    const int* __restrict__ cnt, const int* __restrict__ offset,
    const int* __restrict__ slot_edge,
    const float* __restrict__ msg, const float* __restrict__ ext_e,
    const int* __restrict__ met_sub, const float* __restrict__ sto_sub,
    const float* __restrict__ sub_b2,
    const float* __restrict__ rate_w1, const float* __restrict__ rate_b1,
    const float* __restrict__ rate_w2, const float* __restrict__ rate_b2,
    const float* __restrict__ log_k,
    float* __restrict__ v, float* __restrict__ total)
{
    __shared__ __align__(16) float sR1[512];
    __shared__ float sRB1[64];
    __shared__ float sR2[64];
    __shared__ float sB2[8];
    __shared__ float sRB2;
    int t = threadIdx.x;
    for (int i = t; i < 512; i += 256) sR1[i] = rate_w1[i];
    for (int i = t; i < 64;  i += 256) { sRB1[i] = rate_b1[i]; sR2[i] = rate_w2[i]; }
    if (t < 8) sB2[t] = sub_b2[t];
    if (t == 64) sRB2 = rate_b2[0];
    __syncthreads();

    int r = blockIdx.x * 256 + t;
    if (r >= NRXN) return;
    int n = cnt[r];
    int base = offset[r];
    float fn = (float)n;

    float h0 = fn * sB2[0], h1 = fn * sB2[1], h2 = fn * sB2[2], h3 = fn * sB2[3];
    float h4 = fn * sB2[4], h5 = fn * sB2[5], h6 = fn * sB2[6], h7 = fn * sB2[7];
    float exs = 0.f;
    for (int i = 0; i < n; ++i) {
        int e = slot_edge[base + i];
        const float4* mp = (const float4*)&msg[(size_t)e * 8];
        float4 a = mp[0], b = mp[1];
        h0 += a.x; h1 += a.y; h2 += a.z; h3 += a.w;
        h4 += b.x; h5 += b.y; h6 += b.z; h7 += b.w;
        exs += ext_e[e];
    }

    float acc = sRB2;
    #pragma unroll 4
    for (int j = 0; j < 64; ++j) {
        float z = sRB1[j];
        z = fmaf(h0, sR1[j],       z);
        z = fmaf(h1, sR1[64 + j],  z);
        z = fmaf(h2, sR1[128 + j], z);
        z = fmaf(h3, sR1[192 + j], z);
        z = fmaf(h4, sR1[256 + j], z);
        z = fmaf(h5, sR1[320 + j], z);
        z = fmaf(h6, sR1[384 + j], z);
        z = fmaf(h7, sR1[448 + j], z);
        acc = fmaf(fast_tanh(z), sR2[j], acc);
    }
    float nmax = fmaxf(fn, 1.0f);
    float ext_mean = 2.0f * exs * __builtin_amdgcn_rcpf(nmax);
    float kk = exp2f(log_k[r] * LOG2_10);
    float vr = kk * ext_mean * acc;
    v[r] = vr;

    // consumption scatter (pre-limit v, per reference)
    float cterm = vr * DT_C;
    for (int i = 0; i < n; ++i) {
        int e = slot_edge[base + i];
        atomicAdd(&total[met_sub[e]], sto_sub[e] * cterm);
    }
}

// ---- 7. per-metabolite scale ------------------------------------------------
__global__ __launch_bounds__(256) void k_met(
    const float* __restrict__ x, const float* __restrict__ total,
    float* __restrict__ met_scale)
{
    int m = blockIdx.x * 256 + threadIdx.x;
    if (m >= NMET) return;
    float c = x[(size_t)m * 8 + 3];
    float tot = total[m];
    float ms = 1.0f;
    if (tot > 1e-12f) ms = fminf(c / tot, 1.0f);
    met_scale[m] = ms;
}

// ---- 8. per-reaction min over edges + v scale ------------------------------
__global__ __launch_bounds__(256) void k_rscale(
    const int* __restrict__ cnt, const int* __restrict__ offset,
    const int* __restrict__ slot_edge, const int* __restrict__ met_sub,
    const float* __restrict__ met_scale, float* __restrict__ v)
{
    int r = blockIdx.x * 256 + threadIdx.x;
    if (r >= NRXN) return;
    int n = cnt[r];
    int base = offset[r];
    float ms = 1.0f;
    for (int i = 0; i < n; ++i) {
        int e = slot_edge[base + i];
        ms = fminf(ms, met_scale[met_sub[e]]);
    }
    v[r] *= ms;
}

// ======================= bucket sort replaces k_contrib =====================

// ---- B1. per-block bucket histogram (LDS atomics, no global atomics) -------
__global__ __launch_bounds__(256) void k_bcount(
    const int* __restrict__ met_all, int* __restrict__ blockHist)
{
    __shared__ int h[NBUCK];
    int t = threadIdx.x;
    for (int b = t; b < NBUCK; b += 256) h[b] = 0;
    __syncthreads();
    int base = blockIdx.x * EB;
    for (int i = t; i < EB; i += 256) {
        int e = base + i;
        if (e < EALL) atomicAdd(&h[met_all[e] >> BSHIFT], 1);
    }
    __syncthreads();
    for (int b = t; b < NBUCK; b += 256)
        blockHist[(size_t)b * NB + blockIdx.x] = h[b];   // bucket-major
}

// ---- B2. per-bucket scan over the NB block counts (in place -> exclusive) --
__global__ __launch_bounds__(256) void k_bscan(
    int* __restrict__ blockHist, int* __restrict__ btotal)
{
    __shared__ int lds[256];
    int b = blockIdx.x;
    int t = threadIdx.x;
    int val = (t < NB) ? blockHist[(size_t)b * NB + t] : 0;
    lds[t] = val;
    __syncthreads();
    for (int off = 1; off < 256; off <<= 1) {
        int add = (t >= off) ? lds[t - off] : 0;
        __syncthreads();
        lds[t] += add;
        __syncthreads();
    }
    if (t < NB) blockHist[(size_t)b * NB + t] = lds[t] - val;
    if (t == NB - 1) btotal[b] = lds[t];
}

// ---- B3. one-block scan of bucket totals -> bucketStart --------------------
__global__ __launch_bounds__(512) void k_bstart(
    const int* __restrict__ btotal, int* __restrict__ bucketStart)
{
    __shared__ int lds[512];
    int t = threadIdx.x;
    int val = (t < NBUCK) ? btotal[t] : 0;
    lds[t] = val;
    __syncthreads();
    for (int off = 1; off < 512; off <<= 1) {
        int add = (t >= off) ? lds[t - off] : 0;
        __syncthreads();
        lds[t] += add;
        __syncthreads();
    }
    if (t < NBUCK) bucketStart[t] = lds[t] - val;
    if (t == 511) bucketStart[NBUCK] = lds[511];   // == EALL
}

// ---- B4. scatter (met,val) records into bucket-grouped slots (plain stores)-
__global__ __launch_bounds__(256) void k_bscatter(
    const int* __restrict__ met_all, const int* __restrict__ rxn_all,
    const float* __restrict__ sto_all, const float* __restrict__ v,
    const int* __restrict__ blockHist, const int* __restrict__ bucketStart,
    uint2* __restrict__ recs)
{
    __shared__ int h[NBUCK];
    __shared__ int bbase[NBUCK];
    int t = threadIdx.x;
    for (int b = t; b < NBUCK; b += 256) {
        h[b] = 0;
        bbase[b] = bucketStart[b] + blockHist[(size_t)b * NB + blockIdx.x];
    }
    __syncthreads();
    int base = blockIdx.x * EB;
    for (int i = t; i < EB; i += 256) {
        int e = base + i;
        if (e < EALL) {
            int m = met_all[e];
            int b = m >> BSHIFT;
            float val = sto_all[e] * v[rxn_all[e]];
            int r = atomicAdd(&h[b], 1);
            uint2 rec;
            rec.x = (unsigned)m;
            rec.y = __float_as_uint(val);
            recs[bbase[b] + r] = rec;
        }
    }
}

// ---- B5. per-bucket accumulate in LDS + homeostasis epilogue ---------------
__global__ __launch_bounds__(256) void k_baccum(
    const uint2* __restrict__ recs, const int* __restrict__ bucketStart,
    const float* __restrict__ x, float* __restrict__ out)
{
    __shared__ float acc[512];
    int b = blockIdx.x;
    int t = threadIdx.x;
    for (int j = t; j < 512; j += 256) acc[j] = 0.f;
    __syncthreads();
    int s = bucketStart[b], epos = bucketStart[b + 1];
    for (int i = s + t; i < epos; i += 256) {
        uint2 rec = recs[i];
        atomicAdd(&acc[rec.x & 511], __uint_as_float(rec.y));
    }
    __syncthreads();
    int mbase = b << BSHIFT;
    for (int j = t; j < 512; j += 256) {
        int m = mbase + j;
        if (m < NMET) {
            float c = x[(size_t)m * 8 + 3];
            out[m] = acc[j] - HOMEO_C * (c - C_TARGET);
        }
    }
}

extern "C" void kernel_launch(void* const* d_in, const int* in_sizes, int n_in,
                              void* d_out, int out_size, void* d_ws, size_t ws_size,
                              hipStream_t stream) {
    const float* x       = (const float*)d_in[0];
    const int*   met_sub = (const int*)  d_in[1];
    const int*   rxn_sub = (const int*)  d_in[2];
    const float* sto_sub = (const float*)d_in[3];
    const int*   met_all = (const int*)  d_in[4];
    const int*   rxn_all = (const int*)  d_in[5];
    const float* sto_all = (const float*)d_in[6];
    const float* sub_w1  = (const float*)d_in[7];
    const float* sub_b1  = (const float*)d_in[8];
    const float* sub_w2  = (const float*)d_in[9];
    const float* sub_b2  = (const float*)d_in[10];
    const float* rate_w1 = (const float*)d_in[11];
    const float* rate_b1 = (const float*)d_in[12];
    const float* rate_w2 = (const float*)d_in[13];
    const float* rate_b2 = (const float*)d_in[14];
    const float* log_k   = (const float*)d_in[15];

    char* ws = (char*)d_ws;
    // ---- zeroed region (atomic accumulators), contiguous at ws start ----
    int*   cnt       = (int*)ws;                        // NRXN   [zeroed]
    float* total     = (float*)(cnt + NRXN);            // NMET   [zeroed]
    // ---- fully-overwritten region ----
    int*   rank      = (int*)(total + NMET);            // ESUB
    int*   offset    = rank + ESUB;                     // NRXN
    int*   bsum      = offset + NRXN;                   // 2048
    int*   boff      = bsum + 2048;                     // 2048
    int*   slot_edge = boff + 2048;                     // ESUB
    float* msg       = (float*)(slot_edge + ESUB);      // ESUB*8
    float* ext_e     = msg + (size_t)ESUB * 8;          // ESUB
    float* v         = ext_e + ESUB;                    // NRXN
    float* met_scale = v + NRXN;                        // NMET
    int*   blockHist = (int*)(met_scale + NMET);        // NBUCK*NB
    int*   btotal    = blockHist + (size_t)NBUCK * NB;  // NBUCK
    int*   bucketStart = btotal + NBUCK;                // NBUCK+1
    uint2* recs      = (uint2*)(bucketStart + NBUCK + 1 +
                                ((NBUCK + 1) & 1));     // EALL records (8B-aligned)
    float* out       = (float*)d_out;

    // zero atomic accumulators: cnt + total are contiguous
    hipMemsetAsync(d_ws, 0, (size_t)(NRXN + NMET) * sizeof(int), stream);

    dim3 blk(256);
    k_hist_msg<<<dim3((ESUB + 255) / 256), blk, 0, stream>>>(
        x, met_sub, rxn_sub, sto_sub, sub_w1, sub_b1, sub_w2,
        cnt, rank, msg, ext_e);
    k_bsum<<<dim3(NBLK), blk, 0, stream>>>(cnt, bsum);
    k_scan_top<<<dim3(1), blk, 0, stream>>>(bsum, boff, NBLK);
    k_offsets<<<dim3(NBLK), blk, 0, stream>>>(cnt, boff, offset);
    k_scatter<<<dim3((ESUB + 255) / 256), blk, 0, stream>>>(
        rxn_sub, offset, rank, slot_edge);
    // bucket-sort count/scan for contrib (independent of v; any order ok)
    k_bcount<<<dim3(NB), blk, 0, stream>>>(met_all, blockHist);
    k_bscan<<<dim3(NBUCK), blk, 0, stream>>>(blockHist, btotal);
    k_bstart<<<dim3(1), dim3(512), 0, stream>>>(btotal, bucketStart);
    k_rxn3<<<dim3((NRXN + 255) / 256), blk, 0, stream>>>(
        cnt, offset, slot_edge, msg, ext_e, met_sub, sto_sub, sub_b2,
        rate_w1, rate_b1, rate_w2, rate_b2, log_k, v, total);
    k_met<<<dim3((NMET + 255) / 256), blk, 0, stream>>>(x, total, met_scale);
    k_rscale<<<dim3((NRXN + 255) / 256), blk, 0, stream>>>(
        cnt, offset, slot_edge, met_sub, met_scale, v);
    k_bscatter<<<dim3(NB), blk, 0, stream>>>(
        met_all, rxn_all, sto_all, v, blockHist, bucketStart, recs);
    k_baccum<<<dim3(NBUCK), blk, 0, stream>>>(recs, bucketStart, x, out);
}